// Round 13
// baseline (718.855 us; speedup 1.0000x reference)
//
#include <hip/hip_runtime.h>
#include <hip/hip_bf16.h>
#include <math.h>

#define NN   6000
#define N2   12000
#define DD   128
#define RR   1000
#define CAP  96
#define CAPR 48
#define MAXN_F 0.996f

typedef short  bf16x8 __attribute__((ext_vector_type(8)));
typedef float  f32x4  __attribute__((ext_vector_type(4)));

// ---------------- module-global scratch ----------------
__device__ int      g_dt[19];
__device__ unsigned g_csri[N2 * CAP];
__device__ int      g_cnt[N2];
__device__ float    g_seq[N2 * 3 * DD];
__device__ unsigned short g_seqb[N2 * 3 * DD];
__device__ unsigned short g_hhb[N2 * 256];
__device__ float    g_es[2][N2];
__device__ float    g_ed[2][N2];
__device__ unsigned short g_qkvb[(size_t)N2 * 3 * 768];
__device__ unsigned short g_ob[(size_t)N2 * 3 * 256];
__device__ float    g_fc[N2 * 3 * DD];
__device__ float    g_t[N2 * DD];
__device__ float    g_t2[N2 * DD];
// packed weights
__device__ unsigned short g_WgatT[2][256 * DD];
__device__ unsigned short g_WqkvT[768 * DD];
__device__ unsigned short g_WfcT[DD * 256];
__device__ float    g_WhgcT[2][DD * DD];

__device__ __forceinline__ float ldin(const void* p, size_t i, int bf) {
    if (bf) return __uint_as_float(((unsigned)((const unsigned short*)p)[i]) << 16);
    return ((const float*)p)[i];
}
__device__ __forceinline__ unsigned short f2b(float f) {
    unsigned u = __float_as_uint(f);
    u += 0x7FFFu + ((u >> 16) & 1u);
    return (unsigned short)(u >> 16);
}
__device__ __forceinline__ float b2f(unsigned short b) {
    return __uint_as_float(((unsigned)b) << 16);
}
__device__ __forceinline__ float adjval(int c) {   // bf16(1/c), as the dataset quantized it
    return b2f(f2b(1.0f / (float)c));
}

// ---- wave64 shuffle reductions ----
__device__ __forceinline__ float wsum(float v) {
    #pragma unroll
    for (int o = 32; o > 0; o >>= 1) v += __shfl_xor(v, o, 64);
    return v;
}
__device__ __forceinline__ float wmax(float v) {
    #pragma unroll
    for (int o = 32; o > 0; o >>= 1) v = fmaxf(v, __shfl_xor(v, o, 64));
    return v;
}
__device__ __forceinline__ float b128sum(float v, float* r4) {
    v = wsum(v);
    if ((threadIdx.x & 63) == 0) r4[threadIdx.x >> 6] = v;
    __syncthreads();
    float r = r4[0] + r4[1];
    __syncthreads();
    return r;
}
__device__ __forceinline__ void b128sum2(float v0, float v1, float* r4, float& o0, float& o1) {
    v0 = wsum(v0); v1 = wsum(v1);
    int w = threadIdx.x >> 6;
    if ((threadIdx.x & 63) == 0) { r4[w * 2] = v0; r4[w * 2 + 1] = v1; }
    __syncthreads();
    o0 = r4[0] + r4[2]; o1 = r4[1] + r4[3];
    __syncthreads();
}
__device__ __forceinline__ void b128max2(float v0, float v1, float* r4, float& o0, float& o1) {
    v0 = wmax(v0); v1 = wmax(v1);
    int w = threadIdx.x >> 6;
    if ((threadIdx.x & 63) == 0) { r4[w * 2] = v0; r4[w * 2 + 1] = v1; }
    __syncthreads();
    o0 = fmaxf(r4[0], r4[2]); o1 = fmaxf(r4[1], r4[3]);
    __syncthreads();
}
// half-aware reductions for 256-thread blocks handling 2 independent nodes
__device__ __forceinline__ float h128sum(float v, float* r8) {
    v = wsum(v);
    int w = threadIdx.x >> 6;
    if ((threadIdx.x & 63) == 0) r8[w] = v;
    __syncthreads();
    int h = threadIdx.x >> 7;
    float r = r8[2 * h] + r8[2 * h + 1];
    __syncthreads();
    return r;
}
__device__ __forceinline__ void h128sum2(float v0, float v1, float* r8, float& o0, float& o1) {
    v0 = wsum(v0); v1 = wsum(v1);
    int w = threadIdx.x >> 6;
    if ((threadIdx.x & 63) == 0) { r8[w * 2] = v0; r8[w * 2 + 1] = v1; }
    __syncthreads();
    int h = threadIdx.x >> 7;
    o0 = r8[4 * h] + r8[4 * h + 2];
    o1 = r8[4 * h + 1] + r8[4 * h + 3];
    __syncthreads();
}

struct P19 { const void* p[19]; };

__global__ void detect_all(P19 ptrs) {
    const int sizes[19] = {768000,768000,128000,128000,36000000,36000000,6000000,6000000,
                           65536,512,512,32768,32768,32768,32768,128,128,32768,256};
    int slot = blockIdx.x;
    const unsigned* p = (const unsigned*)ptrs.p[slot];
    __shared__ int votes[2];
    if (threadIdx.x == 0) { votes[0] = 0; votes[1] = 0; }
    __syncthreads();
    int nwords = sizes[slot] / 2;
    if (nwords > 0) {
        int nsamp = nwords < 4096 ? nwords : 4096;
        int stride = nwords / nsamp; if (stride < 1) stride = 1;
        for (int s = threadIdx.x; s < nsamp; s += blockDim.x) {
            unsigned lo = p[(size_t)s * stride] & 0xFFFFu;
            if (lo) {
                unsigned e = (lo >> 7) & 0xFFu;
                if (e >= 100u && e <= 140u) atomicAdd(&votes[1], 1);
                else                        atomicAdd(&votes[0], 1);
            }
        }
    }
    __syncthreads();
    if (threadIdx.x == 0) g_dt[slot] = (votes[1] > votes[0]) ? 1 : 0;
}

// ---------------- hyperbolic device cores (half-aware) ----------------
__device__ __forceinline__ float bias_inline(const void* hgc_b, int layer, int d, float* r8,
                                             float& y2) {
    float bv = ldin(hgc_b, (size_t)layer * DD + d, g_dt[18]);
    float ss = h128sum(bv * bv, r8);
    float nrm = fmaxf(sqrtf(ss), 1e-15f);
    float t = tanhf(nrm);
    float v = t / nrm * bv;
    float vn = t;
    if (t > MAXN_F) { v *= MAXN_F / t; vn = MAXN_F; }
    y2 = vn * vn;
    return v;
}

__device__ __forceinline__ float hgc_lin_h(const float* uh, float* r8, int layer, int d,
                                           float y, float y2) {
    float mv = 0.f;
    #pragma unroll 4
    for (int j = 0; j < DD; j++) mv = fmaf(g_WhgcT[layer][j * 128 + d], uh[j], mv);
    float ss2 = h128sum(mv * mv, r8);
    float nm = fmaxf(sqrtf(ss2), 1e-15f);
    float t2 = tanhf(nm);
    float x = t2 / nm * mv;
    float xn = t2;
    if (t2 > MAXN_F) { x *= MAXN_F / t2; xn = MAXN_F; }
    float x2 = xn * xn;
    float xy = h128sum(x * y, r8);
    float num = (1.f + 2.f * xy + y2) * x + (1.f - x2) * y;
    float den = 1.f + 2.f * xy + x2 * y2;
    den = (fabsf(den) < 1e-15f) ? 1e-15f : den;
    float hv2 = num / den;
    float s3 = h128sum(hv2 * hv2, r8);
    float nn = fmaxf(sqrtf(s3), 1e-15f);
    if (nn > MAXN_F) { hv2 *= MAXN_F / nn; nn = MAXN_F; }
    return atanhf(fminf(nn, 1.f - 1e-7f)) / nn * hv2;
}

__device__ __forceinline__ float hgc_agg_h(const float* tin, int n, int which, float* r8,
                                           int d, unsigned* sidxh) {
    int c = min(g_cnt[n], CAP);
    if (d < c)
        sidxh[d] = (g_csri[(size_t)n * CAP + d] + (unsigned)(which * NN)) * 128u + (unsigned)d;
    __syncthreads();
    float acc = 0.f;
    int j = 0;
    for (; j + 4 <= c; j += 4) {
        float v0 = tin[(size_t)sidxh[j]];
        float v1 = tin[(size_t)sidxh[j + 1]];
        float v2 = tin[(size_t)sidxh[j + 2]];
        float v3 = tin[(size_t)sidxh[j + 3]];
        acc += (v0 + v1) + (v2 + v3);
    }
    for (; j < c; j++) acc += tin[(size_t)sidxh[j]];
    acc *= (c > 0) ? adjval(c) : 0.f;
    __syncthreads();
    float ss = h128sum(acc * acc, r8);
    float nm = fmaxf(sqrtf(ss), 1e-15f);
    float t = tanhf(nm);
    float x = t / nm * acc;
    float xn = t;
    if (t > MAXN_F) { x *= MAXN_F / t; xn = MAXN_F; }
    float u = atanhf(fminf(xn, 1.f - 1e-7f)) / fmaxf(xn, 1e-15f) * x;
    u = fmaxf(u, 0.f);
    float ss2 = h128sum(u * u, r8);
    float nm2 = fmaxf(sqrtf(ss2), 1e-15f);
    float t2 = tanhf(nm2);
    float x2 = t2 / nm2 * u;
    float xn2 = t2;
    if (t2 > MAXN_F) { x2 *= MAXN_F / t2; xn2 = MAXN_F; }
    return atanhf(fminf(xn2, 1.f - 1e-7f)) / fmaxf(xn2, 1e-15f) * x2;
}

// ---------------- front_small: rel_agg + ent_init + weight prep ----------------
// blocks [0,6000): rel_agg 2 nodes/block; [6000,12000): ent_init 2 nodes/block; [12000,12128): prep
__global__ __launch_bounds__(256) void front_small(P19 in, float* __restrict__ out) {
    int b = blockIdx.x;
    int tid = threadIdx.x;
    if (b < 6000) {
        int half = tid >> 7, d = tid & 127;
        int n = b * 2 + half;
        int which = n >= NN ? 1 : 0;
        const void* radj = in.p[6 + which];
        const void* rel  = in.p[2 + which];
        const int bfa = g_dt[6 + which], bfr = g_dt[2 + which];
        int row = n - which * NN;
        __shared__ int list[2][CAPR];
        __shared__ int cs[2];
        if (d == 0) cs[half] = 0;
        __syncthreads();
        if (bfa) {
            const uint4* p = (const uint4*)((const unsigned short*)radj + (size_t)row * RR);
            if (d < RR / 8) {
                uint4 w4 = p[d];
                unsigned ws[4] = {w4.x, w4.y, w4.z, w4.w};
                #pragma unroll
                for (int h = 0; h < 4; h++) {
                    unsigned lo = ws[h] & 0xFFFFu, hi = ws[h] >> 16;
                    if (lo && !(lo & 0x8000u)) { int q = atomicAdd(&cs[half], 1); if (q < CAPR) list[half][q] = d * 8 + h * 2; }
                    if (hi && !(hi & 0x8000u)) { int q = atomicAdd(&cs[half], 1); if (q < CAPR) list[half][q] = d * 8 + h * 2 + 1; }
                }
            }
        } else {
            const float4* p = (const float4*)((const float*)radj + (size_t)row * RR);
            for (int i = d; i < RR / 4; i += 128) {
                float4 w4 = p[i];
                float vs[4] = {w4.x, w4.y, w4.z, w4.w};
                #pragma unroll
                for (int h = 0; h < 4; h++)
                    if (vs[h] > 0.f) { int q = atomicAdd(&cs[half], 1); if (q < CAPR) list[half][q] = i * 4 + h; }
            }
        }
        __syncthreads();
        int c = min(cs[half], CAPR);
        float acc = 0.f;
        for (int j = 0; j < c; j++) acc += ldin(rel, (size_t)list[half][j] * DD + d, bfr);
        float r = c ? acc / (float)c : 0.f;
        out[(size_t)n * 256 + 128 + d] = r;
        out[(size_t)(2 * NN + n) * 256 + 128 + d] = r;
    } else if (b < 12000) {
        int half = tid >> 7, d = tid & 127;
        int n = (b - 6000) * 2 + half;
        int which = n >= NN ? 1 : 0;
        __shared__ float r8[8];
        __shared__ float u[2][128];
        float y02;
        float y0 = bias_inline(in.p[18], 0, d, r8, y02);
        float x = ldin(in.p[which], (size_t)(n - which * NN) * DD + d, g_dt[which]);
        g_seq[(size_t)n * 384 + d] = x;
        g_seqb[(size_t)n * 384 + d] = f2b(x);
        float ss = h128sum(x * x, r8);
        float nrm = fmaxf(sqrtf(ss), 1e-15f);
        float t = tanhf(nrm);
        float scale = t / nrm;
        float hn = t;
        if (t > MAXN_F) { scale *= MAXN_F / t; hn = MAXN_F; }
        u[half][d] = atanhf(fminf(hn, 1.f - 1e-7f)) / fmaxf(hn, 1e-15f) * (scale * x);
        __syncthreads();
        g_t[(size_t)n * DD + d] = hgc_lin_h(u[half], r8, 0, d, y0, y02);
    } else {
        int stride = 128 * 256;
        int base = (b - 12000) * 256 + tid;
        const int b8 = g_dt[8], b11 = g_dt[11], b12 = g_dt[12], b13 = g_dt[13],
                  b14 = g_dt[14], b17 = g_dt[17];
        for (int i = base; i < 65536; i += stride) {
            int e = i & 127, d = (i >> 7) & 127, h = (i >> 14) & 1, l = (i >> 15) & 1;
            g_WgatT[l][(h * 128 + e) * DD + d] = f2b(ldin(in.p[8], i, b8));
        }
        for (int i = base; i < 32768; i += stride) {
            int d = i >> 8, e = i & 255;
            g_WqkvT[(size_t)e * DD + d]         = f2b(ldin(in.p[11], i, b11));
            g_WqkvT[(size_t)(256 + e) * DD + d] = f2b(ldin(in.p[12], i, b12));
            g_WqkvT[(size_t)(512 + e) * DD + d] = f2b(ldin(in.p[13], i, b13));
        }
        for (int i = base; i < 32768; i += stride) {
            int e = i >> 7, dd = i & 127;
            g_WfcT[dd * 256 + e] = f2b(ldin(in.p[14], i, b14));
        }
        for (int i = base; i < 32768; i += stride) {
            int j = i & 127, d = (i >> 7) & 127, l = i >> 14;
            g_WhgcT[l][j * 128 + d] = ldin(in.p[17], i, b17);
        }
    }
}

// ---------------- scan ∥ GAT-GEMM with fused scores epilogue ----------------
// blocks [0,scanBlocks): adjacency scan (both graphs); [scanBlocks, scanBlocks+188): GEMM
// gemm: hh[N2 x 256] = seq_layer[N2 x 128] @ WgatT[layer], C bf16; plus es/ed row-dots (head=bn)
__global__ __launch_bounds__(256) void scan_gemm(P19 in, int layer, int scanBlocks) {
    __shared__ __align__(16) unsigned short As[16 * 128 * 8];
    __shared__ __align__(16) unsigned short Bs[16 * 128 * 8];
    int tid = threadIdx.x;
    if (blockIdx.x < (unsigned)scanBlocks) {
        int b = blockIdx.x;
        int which = b >= 1500 ? 1 : 0;
        int row = ((which ? b - 1500 : b) << 2) | (tid >> 6);
        int lane = tid & 63;
        const void* A = in.p[4 + which];
        int gn = which * NN + row;
        unsigned long long below = (1ull << lane) - 1ull;
        int base = 0;
        if (g_dt[4 + which]) {
            const uint4* p = (const uint4*)((const unsigned short*)A + (size_t)row * NN);
            uint4 cur = p[lane];
            for (int it = 0; it < 12; it++) {
                int idx = it * 64 + lane;
                uint4 nxt = {0u, 0u, 0u, 0u};
                if (it < 11) { int ni = idx + 64; if (ni < 750) nxt = p[ni]; }
                unsigned w4[4] = {cur.x, cur.y, cur.z, cur.w};
                #pragma unroll
                for (int h = 0; h < 4; h++) {
                    #pragma unroll
                    for (int s = 0; s < 2; s++) {
                        unsigned v16 = s ? (w4[h] >> 16) : (w4[h] & 0xFFFFu);
                        bool pr = v16 && !(v16 & 0x8000u);
                        unsigned long long m = __ballot(pr);
                        if (m) {
                            if (pr) {
                                int pos = base + __popcll(m & below);
                                if (pos < CAP)
                                    g_csri[(size_t)gn * CAP + pos] = (unsigned)(idx * 8 + h * 2 + s);
                            }
                            base += __popcll(m);
                        }
                    }
                }
                cur = nxt;
            }
        } else {
            const float4* p = (const float4*)((const float*)A + (size_t)row * NN);
            float4 cur = p[lane];
            for (int it = 0; it < 24; it++) {
                int idx = it * 64 + lane;
                float4 nxt = {0.f, 0.f, 0.f, 0.f};
                if (it < 23) { int ni = idx + 64; if (ni < 1500) nxt = p[ni]; }
                float e4[4] = {cur.x, cur.y, cur.z, cur.w};
                #pragma unroll
                for (int h = 0; h < 4; h++) {
                    bool pr = e4[h] > 0.f;
                    unsigned long long m = __ballot(pr);
                    if (m) {
                        if (pr) {
                            int pos = base + __popcll(m & below);
                            if (pos < CAP)
                                g_csri[(size_t)gn * CAP + pos] = (unsigned)(idx * 4 + h);
                        }
                        base += __popcll(m);
                    }
                }
                cur = nxt;
            }
        }
        if (lane == 0) g_cnt[gn] = min(base, CAP);
        return;
    }
    // ---- GEMM branch ----
    int gb = blockIdx.x - scanBlocks;      // 0..187: by = gb>>1, bn = gb&1
    int bm = (gb >> 1) * 128, bn = (gb & 1) * 128;
    const unsigned short* A = g_seqb + layer * 128;
    const int lda = 384;
    const unsigned short* Bt = g_WgatT[layer];
    const int M = N2;
    int lane = tid & 63, w = tid >> 6;
    int q = lane >> 4, ln = lane & 15;
    f32x4 acc[8][2] = {};
    {   // K=128, single slab
        #pragma unroll
        for (int i = 0; i < 8; i++) {
            int combo = w * 8 + i;
            int c = combo >> 1, half = combo & 1;
            int r = half * 64 + lane;
            int gm = bm + r; if (gm >= M) gm = M - 1;
            *(uint4*)&As[(c * 128 + r) * 8] = *(const uint4*)(A + (size_t)gm * lda + c * 8);
            *(uint4*)&Bs[(c * 128 + r) * 8] = *(const uint4*)(Bt + (size_t)(bn + r) * DD + c * 8);
        }
        __syncthreads();
        #pragma unroll
        for (int s = 0; s < 4; s++) {
            bf16x8 bf0 = *(const bf16x8*)&Bs[((s * 4 + q) * 128 + w * 32 + ln) * 8];
            bf16x8 bf1 = *(const bf16x8*)&Bs[((s * 4 + q) * 128 + w * 32 + 16 + ln) * 8];
            #pragma unroll
            for (int mt = 0; mt < 8; mt++) {
                bf16x8 af = *(const bf16x8*)&As[((s * 4 + q) * 128 + mt * 16 + ln) * 8];
                acc[mt][0] = __builtin_amdgcn_mfma_f32_16x16x32_bf16(af, bf0, acc[mt][0], 0, 0, 0);
                acc[mt][1] = __builtin_amdgcn_mfma_f32_16x16x32_bf16(af, bf1, acc[mt][1], 0, 0, 0);
            }
        }
    }
    // C write (bf16 hh)
    #pragma unroll
    for (int mt = 0; mt < 8; mt++) {
        #pragma unroll
        for (int nt = 0; nt < 2; nt++) {
            int gcol = bn + w * 32 + nt * 16 + ln;
            #pragma unroll
            for (int r = 0; r < 4; r++) {
                int grow = bm + mt * 16 + q * 4 + r;
                if (grow < M)
                    g_hhb[(size_t)grow * 256 + gcol] = f2b(acc[mt][nt][r]);
            }
        }
    }
    // scores epilogue: head = bn>>7 (0 or 1); dot rows with a_src/a_dst
    const int head = bn >> 7;
    const int bfs = g_dt[9], bfd = g_dt[10];
    size_t abase = ((size_t)layer * 2 + head) * DD;
    int c0 = w * 32 + ln, c1 = w * 32 + 16 + ln;
    float a0s = ldin(in.p[9],  abase + c0, bfs), a1s = ldin(in.p[9],  abase + c1, bfs);
    float a0d = ldin(in.p[10], abase + c0, bfd), a1d = ldin(in.p[10], abase + c1, bfd);
    __syncthreads();                       // As/Bs free for reuse
    float* pS = (float*)As;                // [4][128]
    float* pD = pS + 512;
    #pragma unroll
    for (int mt = 0; mt < 8; mt++) {
        #pragma unroll
        for (int r = 0; r < 4; r++) {
            int row = mt * 16 + q * 4 + r;
            float ps = acc[mt][0][r] * a0s + acc[mt][1][r] * a1s;
            float pd = acc[mt][0][r] * a0d + acc[mt][1][r] * a1d;
            #pragma unroll
            for (int o = 1; o < 16; o <<= 1) {
                ps += __shfl_xor(ps, o, 64);
                pd += __shfl_xor(pd, o, 64);
            }
            if (ln == 0) { pS[w * 128 + row] = ps; pD[w * 128 + row] = pd; }
        }
    }
    __syncthreads();
    if (tid < 128) {
        int grow = bm + tid;
        if (grow < M) {
            g_es[head][grow] = pS[tid] + pS[128 + tid] + pS[256 + tid] + pS[384 + tid];
            g_ed[head][grow] = pD[tid] + pD[128 + tid] + pD[256 + tid] + pD[384 + tid];
        }
    }
}

// ---------------- generic MFMA bf16 GEMM (qkv / fc) ----------------
template<bool OUT_BF16>
__global__ __launch_bounds__(256) void gemm_mfma(const unsigned short* __restrict__ A, int lda,
                                                 const unsigned short* __restrict__ Bt, int ldb,
                                                 void* __restrict__ C, int ldc, int M, int K) {
    __shared__ __align__(16) unsigned short As[16 * 128 * 8];
    __shared__ __align__(16) unsigned short Bs[16 * 128 * 8];
    int bm = blockIdx.y * 128, bn = blockIdx.x * 128;
    int tid = threadIdx.x;
    int lane = tid & 63, w = tid >> 6;
    int q = lane >> 4, ln = lane & 15;
    f32x4 acc[8][2] = {};
    for (int k0 = 0; k0 < K; k0 += 128) {
        if (k0 > 0) __syncthreads();
        #pragma unroll
        for (int i = 0; i < 8; i++) {
            int combo = w * 8 + i;
            int c = combo >> 1, half = combo & 1;
            int r = half * 64 + lane;
            int gm = bm + r; if (gm >= M) gm = M - 1;
            *(uint4*)&As[(c * 128 + r) * 8] =
                *(const uint4*)(A + (size_t)gm * lda + k0 + c * 8);
            *(uint4*)&Bs[(c * 128 + r) * 8] =
                *(const uint4*)(Bt + (size_t)(bn + r) * ldb + k0 + c * 8);
        }
        __syncthreads();
        #pragma unroll
        for (int s = 0; s < 4; s++) {
            bf16x8 bf0 = *(const bf16x8*)&Bs[((s * 4 + q) * 128 + w * 32 + ln) * 8];
            bf16x8 bf1 = *(const bf16x8*)&Bs[((s * 4 + q) * 128 + w * 32 + 16 + ln) * 8];
            #pragma unroll
            for (int mt = 0; mt < 8; mt++) {
                bf16x8 af = *(const bf16x8*)&As[((s * 4 + q) * 128 + mt * 16 + ln) * 8];
                acc[mt][0] = __builtin_amdgcn_mfma_f32_16x16x32_bf16(af, bf0, acc[mt][0], 0, 0, 0);
                acc[mt][1] = __builtin_amdgcn_mfma_f32_16x16x32_bf16(af, bf1, acc[mt][1], 0, 0, 0);
            }
        }
    }
    #pragma unroll
    for (int mt = 0; mt < 8; mt++) {
        #pragma unroll
        for (int nt = 0; nt < 2; nt++) {
            int gcol = bn + w * 32 + nt * 16 + ln;
            #pragma unroll
            for (int r = 0; r < 4; r++) {
                int grow = bm + mt * 16 + q * 4 + r;
                if (grow < M) {
                    if (OUT_BF16)
                        ((unsigned short*)C)[(size_t)grow * ldc + gcol] = f2b(acc[mt][nt][r]);
                    else
                        ((float*)C)[(size_t)grow * ldc + gcol] = acc[mt][nt][r];
                }
            }
        }
    }
}

// ---------------- GAT attention ----------------
__global__ void gat_attn(int layer) {
    int n = blockIdx.x, d = threadIdx.x;
    int which = n >= NN ? 1 : 0;
    int c = min(g_cnt[n], CAP);
    __shared__ float w0s[CAP], w1s[CAP];
    __shared__ unsigned bases[CAP];
    __shared__ float r4[4];
    __shared__ float sh[256];
    float es0 = g_es[0][n], es1 = g_es[1][n];
    float e0 = -1e30f, e1 = -1e30f;
    if (d < c) {
        int gI = (int)g_csri[(size_t)n * CAP + d] + which * NN;
        bases[d] = (unsigned)gI * 128u;
        e0 = es0 + g_ed[0][gI]; e0 = e0 > 0.f ? e0 : 0.2f * e0;
        e1 = es1 + g_ed[1][gI]; e1 = e1 > 0.f ? e1 : 0.2f * e1;
    }
    float m0, m1, s0, s1;
    b128max2(e0, e1, r4, m0, m1);
    float w0 = (d < c) ? expf(e0 - m0) : 0.f;
    float w1 = (d < c) ? expf(e1 - m1) : 0.f;
    b128sum2(w0, w1, r4, s0, s1);
    if (d < c) { w0s[d] = w0 / fmaxf(s0, 1e-30f); w1s[d] = w1 / fmaxf(s1, 1e-30f); }
    __syncthreads();
    const unsigned* hh32 = (const unsigned*)g_hhb;
    int head = d >> 6;
    const float* wsrc = head ? w1s : w0s;
    float accLo = 0.f, accHi = 0.f;
    int j = 0;
    for (; j + 4 <= c; j += 4) {
        unsigned v0 = hh32[(size_t)bases[j]     + d];
        unsigned v1 = hh32[(size_t)bases[j + 1] + d];
        unsigned v2 = hh32[(size_t)bases[j + 2] + d];
        unsigned v3 = hh32[(size_t)bases[j + 3] + d];
        float g0 = wsrc[j], g1 = wsrc[j + 1], g2 = wsrc[j + 2], g3 = wsrc[j + 3];
        accLo = fmaf(g0, b2f((unsigned short)(v0 & 0xFFFFu)), accLo);
        accHi = fmaf(g0, b2f((unsigned short)(v0 >> 16)), accHi);
        accLo = fmaf(g1, b2f((unsigned short)(v1 & 0xFFFFu)), accLo);
        accHi = fmaf(g1, b2f((unsigned short)(v1 >> 16)), accHi);
        accLo = fmaf(g2, b2f((unsigned short)(v2 & 0xFFFFu)), accLo);
        accHi = fmaf(g2, b2f((unsigned short)(v2 >> 16)), accHi);
        accLo = fmaf(g3, b2f((unsigned short)(v3 & 0xFFFFu)), accLo);
        accHi = fmaf(g3, b2f((unsigned short)(v3 >> 16)), accHi);
    }
    for (; j < c; j++) {
        unsigned wv = hh32[(size_t)bases[j] + d];
        float wgt = wsrc[j];
        accLo = fmaf(wgt, b2f((unsigned short)(wv & 0xFFFFu)), accLo);
        accHi = fmaf(wgt, b2f((unsigned short)(wv >> 16)), accHi);
    }
    sh[2 * d] = accLo; sh[2 * d + 1] = accHi;
    __syncthreads();
    float o = (c > 0) ? 0.5f * (sh[d] + sh[128 + d]) : 0.f;
    o = o > 0.f ? o : expm1f(o);
    __syncthreads();
    float ss = b128sum(o * o, r4);
    float r = o / fmaxf(sqrtf(ss), 1e-12f);
    g_seq[(size_t)n * 384 + (layer + 1) * 128 + d] = r;
    g_seqb[(size_t)n * 384 + (layer + 1) * 128 + d] = f2b(r);
}

// ---------------- combined: MHA attention ∥ hgc_mid ----------------
__global__ __launch_bounds__(256) void attn_mid(const void* __restrict__ hgc_b) {
    int tid = threadIdx.x;
    if (blockIdx.x < N2) {
        int n = blockIdx.x;
        __shared__ float qs[3][256], ks[3][256], vs[3][256], os[3][256];
        __shared__ float att[2][3][3];
        const unsigned* src = (const unsigned*)(g_qkvb + (size_t)n * 3 * 768);
        for (int t = tid; t < 1152; t += 256) {
            unsigned wv = src[t];
            int l = t / 384, r = t - l * 384;
            int sec = r >> 7, e2 = (r & 127) * 2;
            float f0 = b2f((unsigned short)(wv & 0xFFFFu));
            float f1 = b2f((unsigned short)(wv >> 16));
            float* dstp = (sec == 0) ? qs[l] : (sec == 1) ? ks[l] : vs[l];
            dstp[e2] = f0; dstp[e2 + 1] = f1;
        }
        __syncthreads();
        if (tid < 144) {
            int g = tid >> 3, sub = tid & 7;
            int h = g / 9, lm = g % 9, l = lm / 3, m = lm % 3;
            int d0 = h * 128 + sub * 16;
            float acc = 0.f;
            #pragma unroll
            for (int k = 0; k < 16; k++) acc += qs[l][d0 + k] * ks[m][d0 + k];
            #pragma unroll
            for (int o = 1; o < 8; o <<= 1) acc += __shfl_xor(acc, o, 8);
            if (sub == 0) att[h][l][m] = acc * 0.08838834764831845f;
        }
        __syncthreads();
        if (tid < 6) {
            int h = tid / 3, l = tid % 3;
            float mx = fmaxf(att[h][l][0], fmaxf(att[h][l][1], att[h][l][2]));
            float e0 = expf(att[h][l][0] - mx), e1 = expf(att[h][l][1] - mx), e2 = expf(att[h][l][2] - mx);
            float s = fmaxf(e0 + e1 + e2, 1e-30f);
            att[h][l][0] = e0 / s; att[h][l][1] = e1 / s; att[h][l][2] = e2 / s;
        }
        __syncthreads();
        for (int t = tid; t < 768; t += 256) {
            int l = t >> 8, e = t & 255, h = e >> 7;
            os[l][e] = att[h][l][0] * vs[0][e] + att[h][l][1] * vs[1][e] + att[h][l][2] * vs[2][e];
        }
        __syncthreads();
        unsigned* dst = (unsigned*)(g_ob + (size_t)n * 3 * 256);
        for (int t = tid; t < 384; t += 256) {
            int l = t / 128, e2 = (t % 128) * 2;
            dst[t] = (unsigned)f2b(os[l][e2]) | ((unsigned)f2b(os[l][e2 + 1]) << 16);
        }
    } else {
        int half = tid >> 7, d = tid & 127;
        int n = (blockIdx.x - N2) * 2 + half;
        int which = n >= NN ? 1 : 0;
        __shared__ float r8[8];
        __shared__ float u2[2][128];
        __shared__ unsigned sidx[2][CAP];
        float y12;
        float y1 = bias_inline(hgc_b, 1, d, r8, y12);
        float u3 = hgc_agg_h(g_t, n, which, r8, d, sidx[half]);
        u2[half][d] = u3;
        __syncthreads();
        g_t2[(size_t)n * DD + d] = hgc_lin_h(u2[half], r8, 1, d, y1, y12);
    }
}

// ---------------- combined: mha_out ∥ hgc_fin ----------------
__global__ __launch_bounds__(256) void out_fin(const void* __restrict__ g, const void* __restrict__ b,
                                               const void* __restrict__ e0, const void* __restrict__ e1,
                                               float* __restrict__ out) {
    int tid = threadIdx.x;
    int half = tid >> 7, d = tid & 127;
    if (blockIdx.x < 6000) {
        int n = blockIdx.x * 2 + half;
        const int bg = g_dt[15], bb = g_dt[16];
        __shared__ float r8[8];
        float ool[3], mu[3], rstd[3];
        #pragma unroll
        for (int l = 0; l < 3; l++)
            ool[l] = g_fc[(size_t)(n * 3 + l) * 128 + d] + g_seq[(size_t)(n * 3 + l) * 128 + d];
        #pragma unroll
        for (int l = 0; l < 3; l++) {
            float s, ss;
            h128sum2(ool[l], ool[l] * ool[l], r8, s, ss);
            mu[l] = s / 128.f;
            rstd[l] = rsqrtf(ss / 128.f - mu[l] * mu[l] + 1e-6f);
        }
        float acc = 0.f;
        #pragma unroll
        for (int l = 0; l < 3; l++) acc += (ool[l] - mu[l]) * rstd[l];
        out[(size_t)n * 256 + d] = ldin(g, d, bg) * (acc / 3.f) + ldin(b, d, bb);
    } else {
        int n = (blockIdx.x - 6000) * 2 + half;
        int which = n >= NN ? 1 : 0;
        __shared__ float r8[8];
        __shared__ unsigned sidx[2][CAP];
        float u3 = hgc_agg_h(g_t2, n, which, r8, d, sidx[half]);
        float ev = ldin(which ? e1 : e0, (size_t)(n - which * NN) * DD + d, g_dt[which]);
        out[(size_t)(2 * NN + n) * 256 + d] = ev + u3;
    }
}

extern "C" void kernel_launch(void* const* d_in, const int* in_sizes, int n_in,
                              void* d_out, int out_size, void* d_ws, size_t ws_size,
                              hipStream_t stream) {
    const void* ln_g = d_in[15];
    const void* ln_b = d_in[16];
    const void* hgc_b = d_in[18];

    float* out = (float*)d_out;

    unsigned short *p_seqb, *p_qkvb, *p_ob, *p_WqkvT, *p_WfcT;
    float *p_fc;
    hipGetSymbolAddress((void**)&p_seqb,  HIP_SYMBOL(g_seqb));
    hipGetSymbolAddress((void**)&p_qkvb,  HIP_SYMBOL(g_qkvb));
    hipGetSymbolAddress((void**)&p_ob,    HIP_SYMBOL(g_ob));
    hipGetSymbolAddress((void**)&p_WqkvT, HIP_SYMBOL(g_WqkvT));
    hipGetSymbolAddress((void**)&p_WfcT,  HIP_SYMBOL(g_WfcT));
    hipGetSymbolAddress((void**)&p_fc,    HIP_SYMBOL(g_fc));

    P19 ptrs;
    for (int i = 0; i < 19; i++) ptrs.p[i] = d_in[i];
    detect_all<<<19, 256, 0, stream>>>(ptrs);

    front_small<<<12128, 256, 0, stream>>>(ptrs, out);

    // scan (3000) ∥ GAT layer-0 GEMM + fused scores (188)
    scan_gemm<<<3188, 256, 0, stream>>>(ptrs, 0, 3000);
    gat_attn<<<N2, 128, 0, stream>>>(0);
    // GAT layer-1 GEMM + fused scores only
    scan_gemm<<<188, 256, 0, stream>>>(ptrs, 1, 0);
    gat_attn<<<N2, 128, 0, stream>>>(1);

    gemm_mfma<true><<<dim3(6, 282), 256, 0, stream>>>(
        p_seqb, 128, p_WqkvT, DD, p_qkvb, 768, N2 * 3, 128);
    attn_mid<<<N2 + 6000, 256, 0, stream>>>(hgc_b);
    gemm_mfma<false><<<dim3(1, 282), 256, 0, stream>>>(
        p_ob, 256, p_WfcT, 256, p_fc, 128, N2 * 3, 256);
    out_fin<<<12000, 256, 0, stream>>>(ln_g, ln_b, d_in[0], d_in[1], out);
}

// Round 14
// 674.436 us; speedup vs baseline: 1.0659x; 1.0659x over previous
//
#include <hip/hip_runtime.h>
#include <hip/hip_bf16.h>
#include <math.h>

#define NN   6000
#define N2   12000
#define DD   128
#define RR   1000
#define CAP  96
#define CAPR 48
#define MAXN_F 0.996f

typedef short  bf16x8 __attribute__((ext_vector_type(8)));
typedef float  f32x4  __attribute__((ext_vector_type(4)));

// ---------------- module-global scratch ----------------
__device__ int      g_dt[19];
__device__ unsigned g_csri[N2 * CAP];
__device__ int      g_cnt[N2];
__device__ float    g_seq[N2 * 3 * DD];
__device__ unsigned short g_seqb[N2 * 3 * DD];
__device__ unsigned short g_hhb[N2 * 256];
__device__ float    g_es[2][N2];
__device__ float    g_ed[2][N2];
__device__ unsigned short g_qkvb[(size_t)N2 * 3 * 768];
__device__ unsigned short g_ob[(size_t)N2 * 3 * 256];
__device__ float    g_fc[N2 * 3 * DD];
__device__ float    g_t[N2 * DD];
__device__ float    g_t2[N2 * DD];
// packed weights
__device__ unsigned short g_WgatT[2][256 * DD];
__device__ unsigned short g_WqkvT[768 * DD];
__device__ unsigned short g_WfcT[DD * 256];
__device__ float    g_WhgcT[2][DD * DD];

__device__ __forceinline__ float ldin(const void* p, size_t i, int bf) {
    if (bf) return __uint_as_float(((unsigned)((const unsigned short*)p)[i]) << 16);
    return ((const float*)p)[i];
}
__device__ __forceinline__ unsigned short f2b(float f) {
    unsigned u = __float_as_uint(f);
    u += 0x7FFFu + ((u >> 16) & 1u);
    return (unsigned short)(u >> 16);
}
__device__ __forceinline__ float b2f(unsigned short b) {
    return __uint_as_float(((unsigned)b) << 16);
}
__device__ __forceinline__ float adjval(int c) {   // bf16(1/c), as the dataset quantized it
    return b2f(f2b(1.0f / (float)c));
}

// ---- wave64 shuffle reductions ----
__device__ __forceinline__ float wsum(float v) {
    #pragma unroll
    for (int o = 32; o > 0; o >>= 1) v += __shfl_xor(v, o, 64);
    return v;
}
__device__ __forceinline__ float wmax(float v) {
    #pragma unroll
    for (int o = 32; o > 0; o >>= 1) v = fmaxf(v, __shfl_xor(v, o, 64));
    return v;
}
__device__ __forceinline__ float b128sum(float v, float* r4) {
    v = wsum(v);
    if ((threadIdx.x & 63) == 0) r4[threadIdx.x >> 6] = v;
    __syncthreads();
    float r = r4[0] + r4[1];
    __syncthreads();
    return r;
}
__device__ __forceinline__ void b128sum2(float v0, float v1, float* r4, float& o0, float& o1) {
    v0 = wsum(v0); v1 = wsum(v1);
    int w = threadIdx.x >> 6;
    if ((threadIdx.x & 63) == 0) { r4[w * 2] = v0; r4[w * 2 + 1] = v1; }
    __syncthreads();
    o0 = r4[0] + r4[2]; o1 = r4[1] + r4[3];
    __syncthreads();
}
__device__ __forceinline__ void b128max2(float v0, float v1, float* r4, float& o0, float& o1) {
    v0 = wmax(v0); v1 = wmax(v1);
    int w = threadIdx.x >> 6;
    if ((threadIdx.x & 63) == 0) { r4[w * 2] = v0; r4[w * 2 + 1] = v1; }
    __syncthreads();
    o0 = fmaxf(r4[0], r4[2]); o1 = fmaxf(r4[1], r4[3]);
    __syncthreads();
}
// half-aware reductions for 256-thread blocks handling 2 independent nodes
__device__ __forceinline__ float h128sum(float v, float* r8) {
    v = wsum(v);
    int w = threadIdx.x >> 6;
    if ((threadIdx.x & 63) == 0) r8[w] = v;
    __syncthreads();
    int h = threadIdx.x >> 7;
    float r = r8[2 * h] + r8[2 * h + 1];
    __syncthreads();
    return r;
}
__device__ __forceinline__ void h128sum2(float v0, float v1, float* r8, float& o0, float& o1) {
    v0 = wsum(v0); v1 = wsum(v1);
    int w = threadIdx.x >> 6;
    if ((threadIdx.x & 63) == 0) { r8[w * 2] = v0; r8[w * 2 + 1] = v1; }
    __syncthreads();
    int h = threadIdx.x >> 7;
    o0 = r8[4 * h] + r8[4 * h + 2];
    o1 = r8[4 * h + 1] + r8[4 * h + 3];
    __syncthreads();
}

struct P19 { const void* p[19]; };

__global__ void detect_all(P19 ptrs) {
    const int sizes[19] = {768000,768000,128000,128000,36000000,36000000,6000000,6000000,
                           65536,512,512,32768,32768,32768,32768,128,128,32768,256};
    int slot = blockIdx.x;
    const unsigned* p = (const unsigned*)ptrs.p[slot];
    __shared__ int votes[2];
    if (threadIdx.x == 0) { votes[0] = 0; votes[1] = 0; }
    __syncthreads();
    int nwords = sizes[slot] / 2;
    if (nwords > 0) {
        int nsamp = nwords < 4096 ? nwords : 4096;
        int stride = nwords / nsamp; if (stride < 1) stride = 1;
        for (int s = threadIdx.x; s < nsamp; s += blockDim.x) {
            unsigned lo = p[(size_t)s * stride] & 0xFFFFu;
            if (lo) {
                unsigned e = (lo >> 7) & 0xFFu;
                if (e >= 100u && e <= 140u) atomicAdd(&votes[1], 1);
                else                        atomicAdd(&votes[0], 1);
            }
        }
    }
    __syncthreads();
    if (threadIdx.x == 0) g_dt[slot] = (votes[1] > votes[0]) ? 1 : 0;
}

// ---------------- hyperbolic device cores (half-aware) ----------------
__device__ __forceinline__ float bias_inline(const void* hgc_b, int layer, int d, float* r8,
                                             float& y2) {
    float bv = ldin(hgc_b, (size_t)layer * DD + d, g_dt[18]);
    float ss = h128sum(bv * bv, r8);
    float nrm = fmaxf(sqrtf(ss), 1e-15f);
    float t = tanhf(nrm);
    float v = t / nrm * bv;
    float vn = t;
    if (t > MAXN_F) { v *= MAXN_F / t; vn = MAXN_F; }
    y2 = vn * vn;
    return v;
}

__device__ __forceinline__ float hgc_lin_h(const float* uh, float* r8, int layer, int d,
                                           float y, float y2) {
    float mv = 0.f;
    #pragma unroll 4
    for (int j = 0; j < DD; j++) mv = fmaf(g_WhgcT[layer][j * 128 + d], uh[j], mv);
    float ss2 = h128sum(mv * mv, r8);
    float nm = fmaxf(sqrtf(ss2), 1e-15f);
    float t2 = tanhf(nm);
    float x = t2 / nm * mv;
    float xn = t2;
    if (t2 > MAXN_F) { x *= MAXN_F / t2; xn = MAXN_F; }
    float x2 = xn * xn;
    float xy = h128sum(x * y, r8);
    float num = (1.f + 2.f * xy + y2) * x + (1.f - x2) * y;
    float den = 1.f + 2.f * xy + x2 * y2;
    den = (fabsf(den) < 1e-15f) ? 1e-15f : den;
    float hv2 = num / den;
    float s3 = h128sum(hv2 * hv2, r8);
    float nn = fmaxf(sqrtf(s3), 1e-15f);
    if (nn > MAXN_F) { hv2 *= MAXN_F / nn; nn = MAXN_F; }
    return atanhf(fminf(nn, 1.f - 1e-7f)) / nn * hv2;
}

__device__ __forceinline__ float hgc_agg_h(const float* tin, int n, int which, float* r8,
                                           int d, unsigned* sidxh) {
    int c = min(g_cnt[n], CAP);
    if (d < c)
        sidxh[d] = (g_csri[(size_t)n * CAP + d] + (unsigned)(which * NN)) * 128u + (unsigned)d;
    __syncthreads();
    float acc = 0.f;
    int j = 0;
    for (; j + 4 <= c; j += 4) {
        float v0 = tin[(size_t)sidxh[j]];
        float v1 = tin[(size_t)sidxh[j + 1]];
        float v2 = tin[(size_t)sidxh[j + 2]];
        float v3 = tin[(size_t)sidxh[j + 3]];
        acc += (v0 + v1) + (v2 + v3);
    }
    for (; j < c; j++) acc += tin[(size_t)sidxh[j]];
    acc *= (c > 0) ? adjval(c) : 0.f;
    __syncthreads();
    float ss = h128sum(acc * acc, r8);
    float nm = fmaxf(sqrtf(ss), 1e-15f);
    float t = tanhf(nm);
    float x = t / nm * acc;
    float xn = t;
    if (t > MAXN_F) { x *= MAXN_F / t; xn = MAXN_F; }
    float u = atanhf(fminf(xn, 1.f - 1e-7f)) / fmaxf(xn, 1e-15f) * x;
    u = fmaxf(u, 0.f);
    float ss2 = h128sum(u * u, r8);
    float nm2 = fmaxf(sqrtf(ss2), 1e-15f);
    float t2 = tanhf(nm2);
    float x2 = t2 / nm2 * u;
    float xn2 = t2;
    if (t2 > MAXN_F) { x2 *= MAXN_F / t2; xn2 = MAXN_F; }
    return atanhf(fminf(xn2, 1.f - 1e-7f)) / fmaxf(xn2, 1e-15f) * x2;
}

// ---------------- mega front kernel (all branches small-LDS; r12 structure) ----------------
// blocks [0,3000): adjacency scans; [3000,9000): rel_agg; [9000,15000): ent_init; [15000,15128): prep
__global__ __launch_bounds__(256) void front_mega(P19 in, float* __restrict__ out) {
    int b = blockIdx.x;
    int tid = threadIdx.x;
    if (b < 3000) {
        int which = b >= 1500 ? 1 : 0;
        int row = ((which ? b - 1500 : b) << 2) | (tid >> 6);
        int lane = tid & 63;
        const void* A = in.p[4 + which];
        int gn = which * NN + row;
        unsigned long long below = (1ull << lane) - 1ull;
        int base = 0;
        if (g_dt[4 + which]) {
            const uint4* p = (const uint4*)((const unsigned short*)A + (size_t)row * NN);
            uint4 cur = p[lane];
            for (int it = 0; it < 12; it++) {
                int idx = it * 64 + lane;
                uint4 nxt = {0u, 0u, 0u, 0u};
                if (it < 11) { int ni = idx + 64; if (ni < 750) nxt = p[ni]; }
                unsigned w4[4] = {cur.x, cur.y, cur.z, cur.w};
                #pragma unroll
                for (int h = 0; h < 4; h++) {
                    #pragma unroll
                    for (int s = 0; s < 2; s++) {
                        unsigned v16 = s ? (w4[h] >> 16) : (w4[h] & 0xFFFFu);
                        bool pr = v16 && !(v16 & 0x8000u);
                        unsigned long long m = __ballot(pr);
                        if (m) {
                            if (pr) {
                                int pos = base + __popcll(m & below);
                                if (pos < CAP)
                                    g_csri[(size_t)gn * CAP + pos] = (unsigned)(idx * 8 + h * 2 + s);
                            }
                            base += __popcll(m);
                        }
                    }
                }
                cur = nxt;
            }
        } else {
            const float4* p = (const float4*)((const float*)A + (size_t)row * NN);
            float4 cur = p[lane];
            for (int it = 0; it < 24; it++) {
                int idx = it * 64 + lane;
                float4 nxt = {0.f, 0.f, 0.f, 0.f};
                if (it < 23) { int ni = idx + 64; if (ni < 1500) nxt = p[ni]; }
                float e4[4] = {cur.x, cur.y, cur.z, cur.w};
                #pragma unroll
                for (int h = 0; h < 4; h++) {
                    bool pr = e4[h] > 0.f;
                    unsigned long long m = __ballot(pr);
                    if (m) {
                        if (pr) {
                            int pos = base + __popcll(m & below);
                            if (pos < CAP)
                                g_csri[(size_t)gn * CAP + pos] = (unsigned)(idx * 4 + h);
                        }
                        base += __popcll(m);
                    }
                }
                cur = nxt;
            }
        }
        if (lane == 0) g_cnt[gn] = min(base, CAP);
    } else if (b < 9000) {
        int half = tid >> 7, d = tid & 127;
        int n = (b - 3000) * 2 + half;
        int which = n >= NN ? 1 : 0;
        const void* radj = in.p[6 + which];
        const void* rel  = in.p[2 + which];
        const int bfa = g_dt[6 + which], bfr = g_dt[2 + which];
        int row = n - which * NN;
        __shared__ int list[2][CAPR];
        __shared__ int cs[2];
        if (d == 0) cs[half] = 0;
        __syncthreads();
        if (bfa) {
            const uint4* p = (const uint4*)((const unsigned short*)radj + (size_t)row * RR);
            if (d < RR / 8) {
                uint4 w4 = p[d];
                unsigned ws[4] = {w4.x, w4.y, w4.z, w4.w};
                #pragma unroll
                for (int h = 0; h < 4; h++) {
                    unsigned lo = ws[h] & 0xFFFFu, hi = ws[h] >> 16;
                    if (lo && !(lo & 0x8000u)) { int q = atomicAdd(&cs[half], 1); if (q < CAPR) list[half][q] = d * 8 + h * 2; }
                    if (hi && !(hi & 0x8000u)) { int q = atomicAdd(&cs[half], 1); if (q < CAPR) list[half][q] = d * 8 + h * 2 + 1; }
                }
            }
        } else {
            const float4* p = (const float4*)((const float*)radj + (size_t)row * RR);
            for (int i = d; i < RR / 4; i += 128) {
                float4 w4 = p[i];
                float vs[4] = {w4.x, w4.y, w4.z, w4.w};
                #pragma unroll
                for (int h = 0; h < 4; h++)
                    if (vs[h] > 0.f) { int q = atomicAdd(&cs[half], 1); if (q < CAPR) list[half][q] = i * 4 + h; }
            }
        }
        __syncthreads();
        int c = min(cs[half], CAPR);
        float acc = 0.f;
        for (int j = 0; j < c; j++) acc += ldin(rel, (size_t)list[half][j] * DD + d, bfr);
        float r = c ? acc / (float)c : 0.f;
        out[(size_t)n * 256 + 128 + d] = r;
        out[(size_t)(2 * NN + n) * 256 + 128 + d] = r;
    } else if (b < 15000) {
        int half = tid >> 7, d = tid & 127;
        int n = (b - 9000) * 2 + half;
        int which = n >= NN ? 1 : 0;
        __shared__ float r8[8];
        __shared__ float u[2][128];
        float y02;
        float y0 = bias_inline(in.p[18], 0, d, r8, y02);
        float x = ldin(in.p[which], (size_t)(n - which * NN) * DD + d, g_dt[which]);
        g_seq[(size_t)n * 384 + d] = x;
        g_seqb[(size_t)n * 384 + d] = f2b(x);
        float ss = h128sum(x * x, r8);
        float nrm = fmaxf(sqrtf(ss), 1e-15f);
        float t = tanhf(nrm);
        float scale = t / nrm;
        float hn = t;
        if (t > MAXN_F) { scale *= MAXN_F / t; hn = MAXN_F; }
        u[half][d] = atanhf(fminf(hn, 1.f - 1e-7f)) / fmaxf(hn, 1e-15f) * (scale * x);
        __syncthreads();
        g_t[(size_t)n * DD + d] = hgc_lin_h(u[half], r8, 0, d, y0, y02);
    } else {
        int stride = 128 * 256;
        int base = (b - 15000) * 256 + tid;
        const int b8 = g_dt[8], b11 = g_dt[11], b12 = g_dt[12], b13 = g_dt[13],
                  b14 = g_dt[14], b17 = g_dt[17];
        for (int i = base; i < 65536; i += stride) {
            int e = i & 127, d = (i >> 7) & 127, h = (i >> 14) & 1, l = (i >> 15) & 1;
            g_WgatT[l][(h * 128 + e) * DD + d] = f2b(ldin(in.p[8], i, b8));
        }
        for (int i = base; i < 32768; i += stride) {
            int d = i >> 8, e = i & 255;
            g_WqkvT[(size_t)e * DD + d]         = f2b(ldin(in.p[11], i, b11));
            g_WqkvT[(size_t)(256 + e) * DD + d] = f2b(ldin(in.p[12], i, b12));
            g_WqkvT[(size_t)(512 + e) * DD + d] = f2b(ldin(in.p[13], i, b13));
        }
        for (int i = base; i < 32768; i += stride) {
            int e = i >> 7, dd = i & 127;
            g_WfcT[dd * 256 + e] = f2b(ldin(in.p[14], i, b14));
        }
        for (int i = base; i < 32768; i += stride) {
            int j = i & 127, d = (i >> 7) & 127, l = i >> 14;
            g_WhgcT[l][j * 128 + d] = ldin(in.p[17], i, b17);
        }
    }
}

// ---------------- GAT GEMM with fused scores epilogue (GEMM-only kernel) ----------------
// grid 188: bm = (b>>1)*128, bn = (b&1)*128; head = bn>>7
__global__ __launch_bounds__(256) void gemm_scores(P19 in, int layer) {
    __shared__ __align__(16) unsigned short As[16 * 128 * 8];
    __shared__ __align__(16) unsigned short Bs[16 * 128 * 8];
    int tid = threadIdx.x;
    int gb = blockIdx.x;
    int bm = (gb >> 1) * 128, bn = (gb & 1) * 128;
    const unsigned short* A = g_seqb + layer * 128;
    const int lda = 384;
    const unsigned short* Bt = g_WgatT[layer];
    const int M = N2;
    int lane = tid & 63, w = tid >> 6;
    int q = lane >> 4, ln = lane & 15;
    f32x4 acc[8][2] = {};
    {
        #pragma unroll
        for (int i = 0; i < 8; i++) {
            int combo = w * 8 + i;
            int c = combo >> 1, half = combo & 1;
            int r = half * 64 + lane;
            int gm = bm + r; if (gm >= M) gm = M - 1;
            *(uint4*)&As[(c * 128 + r) * 8] = *(const uint4*)(A + (size_t)gm * lda + c * 8);
            *(uint4*)&Bs[(c * 128 + r) * 8] = *(const uint4*)(Bt + (size_t)(bn + r) * DD + c * 8);
        }
        __syncthreads();
        #pragma unroll
        for (int s = 0; s < 4; s++) {
            bf16x8 bf0 = *(const bf16x8*)&Bs[((s * 4 + q) * 128 + w * 32 + ln) * 8];
            bf16x8 bf1 = *(const bf16x8*)&Bs[((s * 4 + q) * 128 + w * 32 + 16 + ln) * 8];
            #pragma unroll
            for (int mt = 0; mt < 8; mt++) {
                bf16x8 af = *(const bf16x8*)&As[((s * 4 + q) * 128 + mt * 16 + ln) * 8];
                acc[mt][0] = __builtin_amdgcn_mfma_f32_16x16x32_bf16(af, bf0, acc[mt][0], 0, 0, 0);
                acc[mt][1] = __builtin_amdgcn_mfma_f32_16x16x32_bf16(af, bf1, acc[mt][1], 0, 0, 0);
            }
        }
    }
    #pragma unroll
    for (int mt = 0; mt < 8; mt++) {
        #pragma unroll
        for (int nt = 0; nt < 2; nt++) {
            int gcol = bn + w * 32 + nt * 16 + ln;
            #pragma unroll
            for (int r = 0; r < 4; r++) {
                int grow = bm + mt * 16 + q * 4 + r;
                if (grow < M)
                    g_hhb[(size_t)grow * 256 + gcol] = f2b(acc[mt][nt][r]);
            }
        }
    }
    const int head = bn >> 7;
    const int bfs = g_dt[9], bfd = g_dt[10];
    size_t abase = ((size_t)layer * 2 + head) * DD;
    int c0 = w * 32 + ln, c1 = w * 32 + 16 + ln;
    float a0s = ldin(in.p[9],  abase + c0, bfs), a1s = ldin(in.p[9],  abase + c1, bfs);
    float a0d = ldin(in.p[10], abase + c0, bfd), a1d = ldin(in.p[10], abase + c1, bfd);
    __syncthreads();
    float* pS = (float*)As;
    float* pD = pS + 512;
    #pragma unroll
    for (int mt = 0; mt < 8; mt++) {
        #pragma unroll
        for (int r = 0; r < 4; r++) {
            int row = mt * 16 + q * 4 + r;
            float ps = acc[mt][0][r] * a0s + acc[mt][1][r] * a1s;
            float pd = acc[mt][0][r] * a0d + acc[mt][1][r] * a1d;
            #pragma unroll
            for (int o = 1; o < 16; o <<= 1) {
                ps += __shfl_xor(ps, o, 64);
                pd += __shfl_xor(pd, o, 64);
            }
            if (ln == 0) { pS[w * 128 + row] = ps; pD[w * 128 + row] = pd; }
        }
    }
    __syncthreads();
    if (tid < 128) {
        int grow = bm + tid;
        if (grow < M) {
            g_es[head][grow] = pS[tid] + pS[128 + tid] + pS[256 + tid] + pS[384 + tid];
            g_ed[head][grow] = pD[tid] + pD[128 + tid] + pD[256 + tid] + pD[384 + tid];
        }
    }
}

// ---------------- generic MFMA bf16 GEMM (qkv / fc) ----------------
template<bool OUT_BF16>
__global__ __launch_bounds__(256) void gemm_mfma(const unsigned short* __restrict__ A, int lda,
                                                 const unsigned short* __restrict__ Bt, int ldb,
                                                 void* __restrict__ C, int ldc, int M, int K) {
    __shared__ __align__(16) unsigned short As[16 * 128 * 8];
    __shared__ __align__(16) unsigned short Bs[16 * 128 * 8];
    int bm = blockIdx.y * 128, bn = blockIdx.x * 128;
    int tid = threadIdx.x;
    int lane = tid & 63, w = tid >> 6;
    int q = lane >> 4, ln = lane & 15;
    f32x4 acc[8][2] = {};
    for (int k0 = 0; k0 < K; k0 += 128) {
        if (k0 > 0) __syncthreads();
        #pragma unroll
        for (int i = 0; i < 8; i++) {
            int combo = w * 8 + i;
            int c = combo >> 1, half = combo & 1;
            int r = half * 64 + lane;
            int gm = bm + r; if (gm >= M) gm = M - 1;
            *(uint4*)&As[(c * 128 + r) * 8] =
                *(const uint4*)(A + (size_t)gm * lda + k0 + c * 8);
            *(uint4*)&Bs[(c * 128 + r) * 8] =
                *(const uint4*)(Bt + (size_t)(bn + r) * ldb + k0 + c * 8);
        }
        __syncthreads();
        #pragma unroll
        for (int s = 0; s < 4; s++) {
            bf16x8 bf0 = *(const bf16x8*)&Bs[((s * 4 + q) * 128 + w * 32 + ln) * 8];
            bf16x8 bf1 = *(const bf16x8*)&Bs[((s * 4 + q) * 128 + w * 32 + 16 + ln) * 8];
            #pragma unroll
            for (int mt = 0; mt < 8; mt++) {
                bf16x8 af = *(const bf16x8*)&As[((s * 4 + q) * 128 + mt * 16 + ln) * 8];
                acc[mt][0] = __builtin_amdgcn_mfma_f32_16x16x32_bf16(af, bf0, acc[mt][0], 0, 0, 0);
                acc[mt][1] = __builtin_amdgcn_mfma_f32_16x16x32_bf16(af, bf1, acc[mt][1], 0, 0, 0);
            }
        }
    }
    #pragma unroll
    for (int mt = 0; mt < 8; mt++) {
        #pragma unroll
        for (int nt = 0; nt < 2; nt++) {
            int gcol = bn + w * 32 + nt * 16 + ln;
            #pragma unroll
            for (int r = 0; r < 4; r++) {
                int grow = bm + mt * 16 + q * 4 + r;
                if (grow < M) {
                    if (OUT_BF16)
                        ((unsigned short*)C)[(size_t)grow * ldc + gcol] = f2b(acc[mt][nt][r]);
                    else
                        ((float*)C)[(size_t)grow * ldc + gcol] = acc[mt][nt][r];
                }
            }
        }
    }
}

// ---------------- GAT attention ----------------
__global__ void gat_attn(int layer) {
    int n = blockIdx.x, d = threadIdx.x;
    int which = n >= NN ? 1 : 0;
    int c = min(g_cnt[n], CAP);
    __shared__ float w0s[CAP], w1s[CAP];
    __shared__ unsigned bases[CAP];
    __shared__ float r4[4];
    __shared__ float sh[256];
    float es0 = g_es[0][n], es1 = g_es[1][n];
    float e0 = -1e30f, e1 = -1e30f;
    if (d < c) {
        int gI = (int)g_csri[(size_t)n * CAP + d] + which * NN;
        bases[d] = (unsigned)gI * 128u;
        e0 = es0 + g_ed[0][gI]; e0 = e0 > 0.f ? e0 : 0.2f * e0;
        e1 = es1 + g_ed[1][gI]; e1 = e1 > 0.f ? e1 : 0.2f * e1;
    }
    float m0, m1, s0, s1;
    b128max2(e0, e1, r4, m0, m1);
    float w0 = (d < c) ? expf(e0 - m0) : 0.f;
    float w1 = (d < c) ? expf(e1 - m1) : 0.f;
    b128sum2(w0, w1, r4, s0, s1);
    if (d < c) { w0s[d] = w0 / fmaxf(s0, 1e-30f); w1s[d] = w1 / fmaxf(s1, 1e-30f); }
    __syncthreads();
    const unsigned* hh32 = (const unsigned*)g_hhb;
    int head = d >> 6;
    const float* wsrc = head ? w1s : w0s;
    float accLo = 0.f, accHi = 0.f;
    int j = 0;
    for (; j + 4 <= c; j += 4) {
        unsigned v0 = hh32[(size_t)bases[j]     + d];
        unsigned v1 = hh32[(size_t)bases[j + 1] + d];
        unsigned v2 = hh32[(size_t)bases[j + 2] + d];
        unsigned v3 = hh32[(size_t)bases[j + 3] + d];
        float g0 = wsrc[j], g1 = wsrc[j + 1], g2 = wsrc[j + 2], g3 = wsrc[j + 3];
        accLo = fmaf(g0, b2f((unsigned short)(v0 & 0xFFFFu)), accLo);
        accHi = fmaf(g0, b2f((unsigned short)(v0 >> 16)), accHi);
        accLo = fmaf(g1, b2f((unsigned short)(v1 & 0xFFFFu)), accLo);
        accHi = fmaf(g1, b2f((unsigned short)(v1 >> 16)), accHi);
        accLo = fmaf(g2, b2f((unsigned short)(v2 & 0xFFFFu)), accLo);
        accHi = fmaf(g2, b2f((unsigned short)(v2 >> 16)), accHi);
        accLo = fmaf(g3, b2f((unsigned short)(v3 & 0xFFFFu)), accLo);
        accHi = fmaf(g3, b2f((unsigned short)(v3 >> 16)), accHi);
    }
    for (; j < c; j++) {
        unsigned wv = hh32[(size_t)bases[j] + d];
        float wgt = wsrc[j];
        accLo = fmaf(wgt, b2f((unsigned short)(wv & 0xFFFFu)), accLo);
        accHi = fmaf(wgt, b2f((unsigned short)(wv >> 16)), accHi);
    }
    sh[2 * d] = accLo; sh[2 * d + 1] = accHi;
    __syncthreads();
    float o = (c > 0) ? 0.5f * (sh[d] + sh[128 + d]) : 0.f;
    o = o > 0.f ? o : expm1f(o);
    __syncthreads();
    float ss = b128sum(o * o, r4);
    float r = o / fmaxf(sqrtf(ss), 1e-12f);
    g_seq[(size_t)n * 384 + (layer + 1) * 128 + d] = r;
    g_seqb[(size_t)n * 384 + (layer + 1) * 128 + d] = f2b(r);
}

// ---------------- combined: MHA attention ∥ hgc_mid ----------------
__global__ __launch_bounds__(256) void attn_mid(const void* __restrict__ hgc_b) {
    int tid = threadIdx.x;
    if (blockIdx.x < N2) {
        int n = blockIdx.x;
        __shared__ float qs[3][256], ks[3][256], vs[3][256], os[3][256];
        __shared__ float att[2][3][3];
        const unsigned* src = (const unsigned*)(g_qkvb + (size_t)n * 3 * 768);
        for (int t = tid; t < 1152; t += 256) {
            unsigned wv = src[t];
            int l = t / 384, r = t - l * 384;
            int sec = r >> 7, e2 = (r & 127) * 2;
            float f0 = b2f((unsigned short)(wv & 0xFFFFu));
            float f1 = b2f((unsigned short)(wv >> 16));
            float* dstp = (sec == 0) ? qs[l] : (sec == 1) ? ks[l] : vs[l];
            dstp[e2] = f0; dstp[e2 + 1] = f1;
        }
        __syncthreads();
        if (tid < 144) {
            int g = tid >> 3, sub = tid & 7;
            int h = g / 9, lm = g % 9, l = lm / 3, m = lm % 3;
            int d0 = h * 128 + sub * 16;
            float acc = 0.f;
            #pragma unroll
            for (int k = 0; k < 16; k++) acc += qs[l][d0 + k] * ks[m][d0 + k];
            #pragma unroll
            for (int o = 1; o < 8; o <<= 1) acc += __shfl_xor(acc, o, 8);
            if (sub == 0) att[h][l][m] = acc * 0.08838834764831845f;
        }
        __syncthreads();
        if (tid < 6) {
            int h = tid / 3, l = tid % 3;
            float mx = fmaxf(att[h][l][0], fmaxf(att[h][l][1], att[h][l][2]));
            float e0 = expf(att[h][l][0] - mx), e1 = expf(att[h][l][1] - mx), e2 = expf(att[h][l][2] - mx);
            float s = fmaxf(e0 + e1 + e2, 1e-30f);
            att[h][l][0] = e0 / s; att[h][l][1] = e1 / s; att[h][l][2] = e2 / s;
        }
        __syncthreads();
        for (int t = tid; t < 768; t += 256) {
            int l = t >> 8, e = t & 255, h = e >> 7;
            os[l][e] = att[h][l][0] * vs[0][e] + att[h][l][1] * vs[1][e] + att[h][l][2] * vs[2][e];
        }
        __syncthreads();
        unsigned* dst = (unsigned*)(g_ob + (size_t)n * 3 * 256);
        for (int t = tid; t < 384; t += 256) {
            int l = t / 128, e2 = (t % 128) * 2;
            dst[t] = (unsigned)f2b(os[l][e2]) | ((unsigned)f2b(os[l][e2 + 1]) << 16);
        }
    } else {
        int half = tid >> 7, d = tid & 127;
        int n = (blockIdx.x - N2) * 2 + half;
        int which = n >= NN ? 1 : 0;
        __shared__ float r8[8];
        __shared__ float u2[2][128];
        __shared__ unsigned sidx[2][CAP];
        float y12;
        float y1 = bias_inline(hgc_b, 1, d, r8, y12);
        float u3 = hgc_agg_h(g_t, n, which, r8, d, sidx[half]);
        u2[half][d] = u3;
        __syncthreads();
        g_t2[(size_t)n * DD + d] = hgc_lin_h(u2[half], r8, 1, d, y1, y12);
    }
}

// ---------------- combined: mha_out ∥ hgc_fin ----------------
__global__ __launch_bounds__(256) void out_fin(const void* __restrict__ g, const void* __restrict__ b,
                                               const void* __restrict__ e0, const void* __restrict__ e1,
                                               float* __restrict__ out) {
    int tid = threadIdx.x;
    int half = tid >> 7, d = tid & 127;
    if (blockIdx.x < 6000) {
        int n = blockIdx.x * 2 + half;
        const int bg = g_dt[15], bb = g_dt[16];
        __shared__ float r8[8];
        float ool[3], mu[3], rstd[3];
        #pragma unroll
        for (int l = 0; l < 3; l++)
            ool[l] = g_fc[(size_t)(n * 3 + l) * 128 + d] + g_seq[(size_t)(n * 3 + l) * 128 + d];
        #pragma unroll
        for (int l = 0; l < 3; l++) {
            float s, ss;
            h128sum2(ool[l], ool[l] * ool[l], r8, s, ss);
            mu[l] = s / 128.f;
            rstd[l] = rsqrtf(ss / 128.f - mu[l] * mu[l] + 1e-6f);
        }
        float acc = 0.f;
        #pragma unroll
        for (int l = 0; l < 3; l++) acc += (ool[l] - mu[l]) * rstd[l];
        out[(size_t)n * 256 + d] = ldin(g, d, bg) * (acc / 3.f) + ldin(b, d, bb);
    } else {
        int n = (blockIdx.x - 6000) * 2 + half;
        int which = n >= NN ? 1 : 0;
        __shared__ float r8[8];
        __shared__ unsigned sidx[2][CAP];
        float u3 = hgc_agg_h(g_t2, n, which, r8, d, sidx[half]);
        float ev = ldin(which ? e1 : e0, (size_t)(n - which * NN) * DD + d, g_dt[which]);
        out[(size_t)(2 * NN + n) * 256 + d] = ev + u3;
    }
}

extern "C" void kernel_launch(void* const* d_in, const int* in_sizes, int n_in,
                              void* d_out, int out_size, void* d_ws, size_t ws_size,
                              hipStream_t stream) {
    const void* ln_g = d_in[15];
    const void* ln_b = d_in[16];
    const void* hgc_b = d_in[18];

    float* out = (float*)d_out;

    unsigned short *p_seqb, *p_qkvb, *p_ob, *p_WqkvT, *p_WfcT;
    float *p_fc;
    hipGetSymbolAddress((void**)&p_seqb,  HIP_SYMBOL(g_seqb));
    hipGetSymbolAddress((void**)&p_qkvb,  HIP_SYMBOL(g_qkvb));
    hipGetSymbolAddress((void**)&p_ob,    HIP_SYMBOL(g_ob));
    hipGetSymbolAddress((void**)&p_WqkvT, HIP_SYMBOL(g_WqkvT));
    hipGetSymbolAddress((void**)&p_WfcT,  HIP_SYMBOL(g_WfcT));
    hipGetSymbolAddress((void**)&p_fc,    HIP_SYMBOL(g_fc));

    P19 ptrs;
    for (int i = 0; i < 19; i++) ptrs.p[i] = d_in[i];
    detect_all<<<19, 256, 0, stream>>>(ptrs);

    front_mega<<<15128, 256, 0, stream>>>(ptrs, out);

    gemm_scores<<<188, 256, 0, stream>>>(ptrs, 0);
    gat_attn<<<N2, 128, 0, stream>>>(0);
    gemm_scores<<<188, 256, 0, stream>>>(ptrs, 1);
    gat_attn<<<N2, 128, 0, stream>>>(1);

    gemm_mfma<true><<<dim3(6, 282), 256, 0, stream>>>(
        p_seqb, 128, p_WqkvT, DD, p_qkvb, 768, N2 * 3, 128);
    attn_mid<<<N2 + 6000, 256, 0, stream>>>(hgc_b);
    gemm_mfma<false><<<dim3(1, 282), 256, 0, stream>>>(
        p_ob, 256, p_WfcT, 256, p_fc, 128, N2 * 3, 256);
    out_fin<<<12000, 256, 0, stream>>>(ln_g, ln_b, d_in[0], d_in[1], out);
}